// Round 12
// baseline (390.397 us; speedup 1.0000x reference)
//
#include <hip/hip_runtime.h>
#include <hip/hip_fp16.h>

#define N 512
#define NF 257        // n_freq = N/2 + 1
#define NB 128        // batch
#define PI_F 3.14159265358979323846f
#define C_SQ2 0.70710678118654752440f

// packed fp32 pair — lowers to v_pk_add_f32 / v_pk_mul_f32 / v_pk_fma_f32
typedef float f2 __attribute__((ext_vector_type(2)));
__device__ __forceinline__ f2 F2(float x, float y) { f2 r; r.x = x; r.y = y; return r; }

__device__ __forceinline__ f2 cmul(f2 a, f2 b) {
    return a.xx * b + F2(-a.y, a.y) * b.yx;
}
__device__ __forceinline__ void bf(f2& a, f2& b) {
    f2 t = b;
    b = a - t;
    a = a + t;
}
__device__ __forceinline__ void bf_tw(f2& a, f2& b, f2 w) {
    f2 t = cmul(b, w);
    b = a - t;
    a = a + t;
}
__device__ __forceinline__ void bf_ni(f2& a, f2& b) {   // tw = -i
    f2 t = F2(b.y, -b.x);
    b = a - t;
    a = a + t;
}
// Compiler-only ordering fence (zero instructions). HW: a wave's DS ops execute
// in issue order; validated R1-R11 (correctness held with no hard drain).
__device__ __forceinline__ void lds_order() {
    asm volatile("" ::: "memory");
}
// cross-lane pull: dst lane l gets v from lane (pa>>2); conflict-free crossbar
__device__ __forceinline__ f2 bperm(int pa, f2 v) {
    int xi = __builtin_amdgcn_ds_bpermute(pa, __float_as_int(v.x));
    int yi = __builtin_amdgcn_ds_bpermute(pa, __float_as_int(v.y));
    return F2(__int_as_float(xi), __int_as_float(yi));
}

__device__ __forceinline__ void fft_phaseA(f2 v[8]) {
    const f2 w64  = F2(C_SQ2, -C_SQ2);    // e^{-i pi/4}
    const f2 w192 = F2(-C_SQ2, -C_SQ2);   // e^{-3i pi/4}
    bf(v[0], v[1]); bf(v[2], v[3]); bf(v[4], v[5]); bf(v[6], v[7]);
    bf(v[0], v[2]); bf_ni(v[1], v[3]); bf(v[4], v[6]); bf_ni(v[5], v[7]);
    bf(v[0], v[4]); bf_tw(v[1], v[5], w64); bf_ni(v[2], v[6]); bf_tw(v[3], v[7], w192);
}
__device__ __forceinline__ void fft_phaseBC(f2 v[8], f2 W1, f2 W1a,
                                            f2 W1n, f2 W1c, f2 W2,
                                            f2 W2n, f2 W3) {
    bf_tw(v[0], v[1], W3); bf_tw(v[2], v[3], W3); bf_tw(v[4], v[5], W3); bf_tw(v[6], v[7], W3);
    bf_tw(v[0], v[2], W2); bf_tw(v[1], v[3], W2n); bf_tw(v[4], v[6], W2); bf_tw(v[5], v[7], W2n);
    bf_tw(v[0], v[4], W1); bf_tw(v[1], v[5], W1a); bf_tw(v[2], v[6], W1n); bf_tw(v[3], v[7], W1c);
}

// 512-pt FFT per wave (single stream), scratch = 576 f2 per wave.
// PHYSICAL-lane core. Input: v[e] = x[64*brev3(e) + brev6(l)];
// output: lane l holds X[64t + l] in v[t].
__device__ __forceinline__ void fft512_core(f2 v[8], f2* st, int l) {
    const f2 w64  = F2(C_SQ2, -C_SQ2);
    const f2 w192 = F2(-C_SQ2, -C_SQ2);
    int g = l >> 3, r = l & 7;
    lds_order();
    fft_phaseA(v);
#pragma unroll
    for (int e = 0; e < 8; e++) st[9 * l + e] = v[e];
    lds_order();
#pragma unroll
    for (int t = 0; t < 8; t++) v[t] = st[72 * g + 9 * t + r];
    float sn, cs;
    __sincosf(-(PI_F / 32.0f) * (float)r, &sn, &cs);
    f2 W1 = F2(cs, sn);
    f2 W2 = cmul(W1, W1);
    f2 W3 = cmul(W2, W2);
    f2 W2n = F2(W2.y, -W2.x);
    f2 W1a = cmul(W1, w64);
    f2 W1n = F2(W1.y, -W1.x);
    f2 W1c = cmul(W1, w192);
    fft_phaseBC(v, W1, W1a, W1n, W1c, W2, W2n, W3);
    lds_order();
#pragma unroll
    for (int t = 0; t < 8; t++) st[72 * g + 9 * t + r] = v[t];
    lds_order();
#pragma unroll
    for (int t = 0; t < 8; t++) v[t] = st[72 * t + l + (l >> 3)];
    __sincosf(-(PI_F / 256.0f) * (float)l, &sn, &cs);
    f2 Wc = F2(cs, sn);
    f2 w2 = cmul(Wc, Wc);
    f2 w4 = cmul(w2, w2);
    f2 w2n = F2(w2.y, -w2.x);
    f2 Wca = cmul(Wc, w64);
    f2 Wcn = F2(Wc.y, -Wc.x);
    f2 Wcc = cmul(Wc, w192);
    fft_phaseBC(v, Wc, Wca, Wcn, Wcc, w2, w2n, w4);
}

// Two independent 512-pt FFTs per wave, interleaved through ONE shared scratch.
// PHYSICAL-lane core; same input/output contract as fft512_core.
__device__ __forceinline__ void fft512_x2(f2 va[8], f2 vb[8], f2* st, int l) {
    const f2 w64  = F2(C_SQ2, -C_SQ2);
    const f2 w192 = F2(-C_SQ2, -C_SQ2);
    int g = l >> 3, r = l & 7;
    fft_phaseA(va); fft_phaseA(vb);
    // ---- transpose 1, interleaved ----
    lds_order();
#pragma unroll
    for (int e = 0; e < 8; e++) st[9 * l + e] = va[e];
    lds_order();
#pragma unroll
    for (int t = 0; t < 8; t++) va[t] = st[72 * g + 9 * t + r];
    lds_order();
#pragma unroll
    for (int e = 0; e < 8; e++) st[9 * l + e] = vb[e];
    lds_order();
#pragma unroll
    for (int t = 0; t < 8; t++) vb[t] = st[72 * g + 9 * t + r];
    float sn, cs;
    __sincosf(-(PI_F / 32.0f) * (float)r, &sn, &cs);
    f2 W1 = F2(cs, sn);
    f2 W2 = cmul(W1, W1);
    f2 W3 = cmul(W2, W2);
    f2 W2n = F2(W2.y, -W2.x);
    f2 W1a = cmul(W1, w64);
    f2 W1n = F2(W1.y, -W1.x);
    f2 W1c = cmul(W1, w192);
    fft_phaseBC(va, W1, W1a, W1n, W1c, W2, W2n, W3);
    fft_phaseBC(vb, W1, W1a, W1n, W1c, W2, W2n, W3);
    // ---- transpose 2, interleaved ----
    lds_order();
#pragma unroll
    for (int t = 0; t < 8; t++) st[72 * g + 9 * t + r] = va[t];
    lds_order();
#pragma unroll
    for (int t = 0; t < 8; t++) va[t] = st[72 * t + l + (l >> 3)];
    lds_order();
#pragma unroll
    for (int t = 0; t < 8; t++) st[72 * g + 9 * t + r] = vb[t];
    lds_order();
#pragma unroll
    for (int t = 0; t < 8; t++) vb[t] = st[72 * t + l + (l >> 3)];
    __sincosf(-(PI_F / 256.0f) * (float)l, &sn, &cs);
    f2 Wc = F2(cs, sn);
    f2 w2 = cmul(Wc, Wc);
    f2 w4 = cmul(w2, w2);
    f2 w2n = F2(w2.y, -w2.x);
    f2 Wca = cmul(Wc, w64);
    f2 Wcn = F2(Wc.y, -Wc.x);
    f2 Wcc = cmul(Wc, w192);
    fft_phaseBC(va, Wc, Wca, Wcn, Wcc, w2, w2n, w4);
    fft_phaseBC(vb, Wc, Wca, Wcn, Wcc, w2, w2n, w4);
}

// Hermitian unpack of one packed-pair FFT into the half2 tile (physical lanes).
__device__ __forceinline__ void unpack_rows(const f2 v[8], __half2* tile,
                                            int lr0, int lr1, int l, int sl) {
#pragma unroll
    for (int t = 0; t <= 4; t++) {
        f2 a = v[7 - t];
        float zfx = __shfl(a.x, sl);
        float zfy = __shfl(a.y, sl);
        if (l == 0) { f2 o = v[(8 - t) & 7]; zfx = o.x; zfy = o.y; }
        f2 z = v[t];
        int col = 64 * t + l;
        if (col < NF) {
            tile[lr0 * 265 + col] = __floats2half2_rn(0.5f * (z.x + zfx), 0.5f * (z.y - zfy));
            tile[lr1 * 265 + col] = __floats2half2_rn(0.5f * (z.y + zfy), 0.5f * (zfx - z.x));
        }
    }
}

// ---------------- Hann window table + zero accumulators (fused) ----------
__global__ __launch_bounds__(256) void hanntab_zero_kernel(float* __restrict__ htab,
                                                           float* __restrict__ accH,
                                                           float* __restrict__ bins,
                                                           float* __restrict__ meanacc) {
    int i = blockIdx.x * 256 + threadIdx.x;
    int r = i >> 9, c = i & (N - 1);
    const float step = (float)N / (float)(N - 1);
    float a = -0.5f * (float)N + (float)r * step;
    float b = -0.5f * (float)N + (float)c * step;
    float rr = sqrtf(a * a + b * b);
    float h = (rr > 256.0f) ? 0.0f : 0.5f * (1.0f + cosf(rr * (PI_F / 256.0f)));
    htab[i] = h;
    if (i < NF * N) accH[i] = 0.0f;
    if (i < 2 * (NF + 1)) bins[i] = 0.0f;
    if (i < NB) meanacc[i] = 0.0f;
}

// ---------------- rowFFT of the Hann window itself (once per launch) ----------
// Hrow layout: [col 0..256][row 0..511] f2 (fp32). Tile-staged coalesced stores.
__global__ __launch_bounds__(512) void hannfft_kernel(const float* __restrict__ htab,
                                                      f2* __restrict__ Hrow) {
    __shared__ __align__(16) float sm[9216];
    int tid = threadIdx.x;
    int w = tid >> 6, l = tid & 63;
    int rowbase = blockIdx.x << 4;
    int r1 = rowbase + 2 * w;
    int pa = (__brev((unsigned)l) >> 26) << 2;          // brev6(l)*4 for bpermute
    int sl = (64 - l) & 63;
    const int bre[8] = {0, 4, 2, 6, 1, 5, 3, 7};        // brev3(e)
    const float* h1 = htab + (size_t)r1 * N + l;        // NATURAL lane order
    const float* h2 = h1 + N;

    f2 v[8];
#pragma unroll
    for (int e = 0; e < 8; e++) {
        int o = bre[e] << 6;
        v[e] = F2(h1[o], h2[o]);
    }
    // lane bit-reversal in-register: v[e](l) <- v[e](brev6(l))
#pragma unroll
    for (int e = 0; e < 8; e++) v[e] = bperm(pa, v[e]);

    f2* st = (f2*)sm + w * 576;
    fft512_core(v, st, l);
    __syncthreads();

    float* tre = sm;            // [16][265]
    float* tim = sm + 4240;
    int lr0 = 2 * w, lr1 = lr0 + 1;
#pragma unroll
    for (int t = 0; t <= 4; t++) {
        f2 a = v[7 - t];
        float zfx = __shfl(a.x, sl);
        float zfy = __shfl(a.y, sl);
        if (l == 0) { f2 o = v[(8 - t) & 7]; zfx = o.x; zfy = o.y; }
        f2 z = v[t];
        int col = 64 * t + l;
        if (col < NF) {
            tre[lr0 * 265 + col] = 0.5f * (z.x + zfx);
            tim[lr0 * 265 + col] = 0.5f * (z.y - zfy);
            tre[lr1 * 265 + col] = 0.5f * (z.y + zfy);
            tim[lr1 * 265 + col] = 0.5f * (zfx - z.x);
        }
    }
    __syncthreads();

    int c0 = tid >> 4, rr = tid & 15;
#pragma unroll
    for (int it = 0; it < 9; it++) {
        int c = it * 32 + c0;
        if (c < NF) {
            Hrow[(size_t)c * N + rowbase + rr] = F2(tre[rr * 265 + c], tim[rr * 265 + c]);
        }
    }
}

// ---------------- row FFT: 4 real rows per wave = 2 interleaved packed FFTs ----
// (512,8): request full 32 waves/CU (4 blocks; LDS 4x37.4KB fits 160KB; VGPR<=64)
__global__ __launch_bounds__(512, 8) void rowfft_kernel(const float* __restrict__ x,
                                                        const float* __restrict__ htab,
                                                        float* __restrict__ meanacc,
                                                        __half2* __restrict__ inter) {
    __shared__ __align__(16) float sm[9216];   // 8 waves x 576 f2 = 36,864 B
    __shared__ float redsum[8];
    int tid = threadIdx.x;
    int w = tid >> 6, l = tid & 63;
    int img = blockIdx.x >> 4;
    int rowbase = (blockIdx.x & 15) << 5;
    int r1 = rowbase + 4 * w;
    int pa = (__brev((unsigned)l) >> 26) << 2;          // brev6(l)*4
    int sl = (64 - l) & 63;
    const int bre[8] = {0, 4, 2, 6, 1, 5, 3, 7};        // brev3(e)
    const float* xp = x + ((size_t)img * N + r1) * N + l;   // NATURAL lane order
    const float* hp = htab + (size_t)r1 * N + l;

    float ax[4][8], hx[4][8];
#pragma unroll
    for (int j = 0; j < 4; j++)
#pragma unroll
        for (int e = 0; e < 8; e++) ax[j][e] = xp[j * N + (bre[e] << 6)];
#pragma unroll
    for (int j = 0; j < 4; j++)
#pragma unroll
        for (int e = 0; e < 8; e++) hx[j][e] = hp[j * N + (bre[e] << 6)];
    __builtin_amdgcn_sched_barrier(0);

    float rsum = 0.0f;
#pragma unroll
    for (int j = 0; j < 4; j++)
#pragma unroll
        for (int e = 0; e < 8; e++) rsum += ax[j][e];

    // elementwise window product in natural distribution, THEN lane bit-reversal
    f2 va[8], vb[8];
#pragma unroll
    for (int e = 0; e < 8; e++) {
        va[e] = bperm(pa, F2(ax[0][e] * hx[0][e], ax[1][e] * hx[1][e]));
        vb[e] = bperm(pa, F2(ax[2][e] * hx[2][e], ax[3][e] * hx[3][e]));
    }

#pragma unroll
    for (int off = 32; off > 0; off >>= 1) rsum += __shfl_down(rsum, off);
    if (l == 0) redsum[w] = rsum;

    f2* st = (f2*)sm + w * 576;
    fft512_x2(va, vb, st, l);
    __syncthreads();   // all waves done with FFT scratch before tile reuse
    if (tid == 0) {
        float s = 0.0f;
#pragma unroll
        for (int i = 0; i < 8; i++) s += redsum[i];
        atomicAdd(meanacc + img, s);
    }

    __half2* tile = (__half2*)sm;    // [32][265]
    unpack_rows(va, tile, 4 * w, 4 * w + 1, l, sl);
    unpack_rows(vb, tile, 4 * w + 2, 4 * w + 3, l, sl);
    __syncthreads();

    // coalesced transposed write: 32 consecutive rows per column (64B segments)
    int c0 = tid >> 5, rr = tid & 31;
#pragma unroll
    for (int it = 0; it < 17; it++) {
        int c = it * 16 + c0;
        if (c < NF) {
            inter[((size_t)img * NF + c) * N + rowbase + rr] = tile[rr * 265 + c];
        }
    }
}

// ---------------- column FFT + |F|^2 half-plane accumulate ----------------
// 4 waves = 4 columns per block; 4 images per y-group with prefetch.
// (256,8): 8 blocks/CU (LDS 8x18.4KB=147KB fits; VGPR<=64) — doubles the
// independent latency chains per SIMD vs the old (256,4).
__global__ __launch_bounds__(256, 8) void colfft_kernel(const __half2* __restrict__ inter,
                                                        const f2* __restrict__ Hrow,
                                                        const float* __restrict__ meanacc,
                                                        float* __restrict__ accH) {
    __shared__ __align__(16) float sm[4608];
    int tid = threadIdx.x;
    int w = tid >> 6, l = tid & 63;
    int col = blockIdx.x * 4 + w;
    int colc = col < NF ? col : NF - 1;
    int b0 = blockIdx.y * 4;
    f2* st = (f2*)sm + w * 576;
    int pa = (__brev((unsigned)l) >> 26) << 2;          // brev6(l)*4
    const int bre[8] = {0, 4, 2, 6, 1, 5, 3, 7};        // brev3(e)

    f2 hc[8];
    const f2* hp = Hrow + (size_t)colc * N + l;         // NATURAL lane order
#pragma unroll
    for (int e = 0; e < 8; e++) hc[e] = hp[bre[e] << 6];

    float mn[4];
#pragma unroll
    for (int i = 0; i < 4; i++)
        mn[i] = meanacc[b0 + i] * (1.0f / ((float)N * (float)N));

    float pw[8];
#pragma unroll
    for (int t = 0; t < 8; t++) pw[t] = 0.0f;

    const size_t istr = (size_t)NF * N;
    const __half2* base = inter + ((size_t)b0 * NF + colc) * N + l;

    __half2 cA[8], cB[8], nA[8], nB[8];
#pragma unroll
    for (int e = 0; e < 8; e++) {
        cA[e] = base[bre[e] << 6];
        cB[e] = base[istr + (bre[e] << 6)];
    }
    __builtin_amdgcn_sched_barrier(0);

#pragma unroll
    for (int it = 0; it < 2; it++) {
        if (it == 0) {
#pragma unroll
            for (int e = 0; e < 8; e++) {
                nA[e] = base[2 * istr + (bre[e] << 6)];
                nB[e] = base[3 * istr + (bre[e] << 6)];
            }
        }
        float mA = mn[2 * it], mB = mn[2 * it + 1];
        f2 va[8], vb[8];
#pragma unroll
        for (int e = 0; e < 8; e++) {
            float2 zA = __half22float2(cA[e]);
            float2 zB = __half22float2(cB[e]);
            va[e] = bperm(pa, F2(zA.x, zA.y) - mA * hc[e]);   // subtract then permute
            vb[e] = bperm(pa, F2(zB.x, zB.y) - mB * hc[e]);
        }
        fft512_x2(va, vb, st, l);
#pragma unroll
        for (int t = 0; t < 8; t++)
            pw[t] += va[t].x * va[t].x + va[t].y * va[t].y
                   + vb[t].x * vb[t].x + vb[t].y * vb[t].y;
#pragma unroll
        for (int e = 0; e < 8; e++) { cA[e] = nA[e]; cB[e] = nB[e]; }
    }

    if (col < NF) {
#pragma unroll
        for (int t = 0; t < 8; t++)
            atomicAdd(&accH[(size_t)col * N + 64 * t + l], pw[t]);
    }
}

// ---------------- finalize: nps2D (with Hermitian mirror) + radial bins ------
__global__ __launch_bounds__(256) void finalize2d_kernel(const float* __restrict__ accH,
                                                         float* __restrict__ out2d,
                                                         float* __restrict__ bins) {
    __shared__ float lsum[NF];
    __shared__ float lcnt[NF];
    int t = threadIdx.x;
    for (int i = t; i < NF; i += 256) { lsum[i] = 0.0f; lcnt[i] = 0.0f; }
    __syncthreads();
    const float scale = (0.1f * 0.1f) / ((float)N * (float)N) / (float)NB;
    int idx = blockIdx.x * 256 + t;
    int stride = gridDim.x * 256;
    for (int p = idx; p < N * N; p += stride) {
        int i = p >> 9, j = p & (N - 1);
        int jm = (j + 256) & 511;
        int col, k;
        if (jm < NF) { col = jm; k = (i + 256) & 511; }        // direct half-plane
        else         { col = 256 - j; k = (256 - i) & 511; }   // Hermitian mirror
        float v = accH[((size_t)col << 9) + k] * scale;
        out2d[p] = v;                                           // coalesced store
        float xi = (float)(i - 256), yj = (float)(j - 256);
        int rad = (int)rintf(sqrtf(xi * xi + yj * yj));
        if (rad < NF) { atomicAdd(&lsum[rad], v); atomicAdd(&lcnt[rad], 1.0f); }
    }
    __syncthreads();
    for (int i = t; i < NF; i += 256) {
        if (lsum[i] != 0.0f || lcnt[i] != 0.0f) {
            atomicAdd(&bins[i], lsum[i]);
            atomicAdd(&bins[NF + 1 + i], lcnt[i]);
        }
    }
}

// ---------------- finalize: nps1D + f1D ----------------
__global__ void finalize1d_kernel(const float* __restrict__ bins, float* __restrict__ out) {
    int t = blockIdx.x * blockDim.x + threadIdx.x;
    if (t < NF) {
        out[t] = bins[t] / bins[NF + 1 + t];                 // nps1D
        out[NF + N * N + t] = (float)t * (5.0f / 256.0f);    // f1D (nyquist = 5)
    }
}

extern "C" void kernel_launch(void* const* d_in, const int* in_sizes, int n_in,
                              void* d_out, int out_size, void* d_ws, size_t ws_size,
                              hipStream_t stream) {
    const float* x = (const float*)d_in[0];
    float* out = (float*)d_out;
    char* ws = (char*)d_ws;

    float* accH    = (float*)ws;                                     // NF*N floats
    float* meanacc = (float*)(ws + (size_t)NF * N * sizeof(float));  // NB floats
    float* bins    = meanacc + NB;                                   // 2*(NF+1) floats
    size_t off_h = (size_t)NF * N * sizeof(float) + NB * sizeof(float)
                   + 2 * (NF + 1) * sizeof(float);
    off_h = (off_h + 255) & ~(size_t)255;
    f2* Hrow = (f2*)(ws + off_h);                                    // [NF][N] f2 ~ 1.05 MB
    size_t off_t = off_h + (size_t)NF * N * sizeof(f2);
    off_t = (off_t + 255) & ~(size_t)255;
    float* htab = (float*)(ws + off_t);                              // [N][N] float = 1 MB
    size_t off_inter = off_t + (size_t)N * N * sizeof(float);
    off_inter = (off_inter + 255) & ~(size_t)255;
    __half2* inter = (__half2*)(ws + off_inter);   // [NB][NF][N] half2 = 67.4 MB

    hanntab_zero_kernel<<<dim3(N * N / 256), dim3(256), 0, stream>>>(htab, accH, bins, meanacc);
    hannfft_kernel<<<dim3(32), dim3(512), 0, stream>>>(htab, Hrow);
    rowfft_kernel<<<dim3(NB * 16), dim3(512), 0, stream>>>(x, htab, meanacc, inter);
    colfft_kernel<<<dim3(65, 32), dim3(256), 0, stream>>>(inter, Hrow, meanacc, accH);
    finalize2d_kernel<<<dim3(512), dim3(256), 0, stream>>>(accH, out + NF, bins);
    finalize1d_kernel<<<dim3(2), dim3(256), 0, stream>>>(bins, out);
}

// Round 13
// 253.455 us; speedup vs baseline: 1.5403x; 1.5403x over previous
//
#include <hip/hip_runtime.h>
#include <hip/hip_fp16.h>

#define N 512
#define NF 257        // n_freq = N/2 + 1
#define NB 128        // batch
#define PI_F 3.14159265358979323846f
#define C_SQ2 0.70710678118654752440f

__device__ __forceinline__ float2 cmul(float2 a, float2 b) {
    return make_float2(a.x * b.x - a.y * b.y, a.x * b.y + a.y * b.x);
}
__device__ __forceinline__ void bf(float2& a, float2& b) {
    float2 t = b;
    b = make_float2(a.x - t.x, a.y - t.y);
    a = make_float2(a.x + t.x, a.y + t.y);
}
__device__ __forceinline__ void bf_tw(float2& a, float2& b, float2 w) {
    float2 t = cmul(b, w);
    b = make_float2(a.x - t.x, a.y - t.y);
    a = make_float2(a.x + t.x, a.y + t.y);
}
__device__ __forceinline__ void bf_ni(float2& a, float2& b) {   // tw = -i
    float2 t = make_float2(b.y, -b.x);
    b = make_float2(a.x - t.x, a.y - t.y);
    a = make_float2(a.x + t.x, a.y + t.y);
}
// Compiler-only ordering fence (zero instructions). HW: a wave's DS ops execute
// in issue order; validated R1-R12 (correctness held with no hard drain).
__device__ __forceinline__ void lds_order() {
    asm volatile("" ::: "memory");
}

__device__ __forceinline__ void fft_phaseA(float2 v[8]) {
    const float2 w64  = make_float2(C_SQ2, -C_SQ2);    // e^{-i pi/4}
    const float2 w192 = make_float2(-C_SQ2, -C_SQ2);   // e^{-3i pi/4}
    bf(v[0], v[1]); bf(v[2], v[3]); bf(v[4], v[5]); bf(v[6], v[7]);
    bf(v[0], v[2]); bf_ni(v[1], v[3]); bf(v[4], v[6]); bf_ni(v[5], v[7]);
    bf(v[0], v[4]); bf_tw(v[1], v[5], w64); bf_ni(v[2], v[6]); bf_tw(v[3], v[7], w192);
}
__device__ __forceinline__ void fft_phaseBC(float2 v[8], float2 W1, float2 W1a,
                                            float2 W1n, float2 W1c, float2 W2,
                                            float2 W2n, float2 W3) {
    bf_tw(v[0], v[1], W3); bf_tw(v[2], v[3], W3); bf_tw(v[4], v[5], W3); bf_tw(v[6], v[7], W3);
    bf_tw(v[0], v[2], W2); bf_tw(v[1], v[3], W2n); bf_tw(v[4], v[6], W2); bf_tw(v[5], v[7], W2n);
    bf_tw(v[0], v[4], W1); bf_tw(v[1], v[5], W1a); bf_tw(v[2], v[6], W1n); bf_tw(v[3], v[7], W1c);
}

// Two independent 512-pt FFTs per wave, interleaved through ONE shared scratch
// (576 float2 per wave). Input: v[e] = x[64*brev3(e)+brev6(l)];
// output: lane l holds X[64t+l] in v[t].
__device__ __forceinline__ void fft512_x2(float2 va[8], float2 vb[8], float2* st, int l) {
    const float2 w64  = make_float2(C_SQ2, -C_SQ2);
    const float2 w192 = make_float2(-C_SQ2, -C_SQ2);
    int g = l >> 3, r = l & 7;
    fft_phaseA(va); fft_phaseA(vb);
    // ---- transpose 1, interleaved ----
    lds_order();
#pragma unroll
    for (int e = 0; e < 8; e++) st[9 * l + e] = va[e];
    lds_order();
#pragma unroll
    for (int t = 0; t < 8; t++) va[t] = st[72 * g + 9 * t + r];
    lds_order();
#pragma unroll
    for (int e = 0; e < 8; e++) st[9 * l + e] = vb[e];
    lds_order();
#pragma unroll
    for (int t = 0; t < 8; t++) vb[t] = st[72 * g + 9 * t + r];
    float sn, cs;
    __sincosf(-(PI_F / 32.0f) * (float)r, &sn, &cs);
    float2 W1 = make_float2(cs, sn);
    float2 W2 = cmul(W1, W1);
    float2 W3 = cmul(W2, W2);
    float2 W2n = make_float2(W2.y, -W2.x);
    float2 W1a = cmul(W1, w64);
    float2 W1n = make_float2(W1.y, -W1.x);
    float2 W1c = cmul(W1, w192);
    fft_phaseBC(va, W1, W1a, W1n, W1c, W2, W2n, W3);
    fft_phaseBC(vb, W1, W1a, W1n, W1c, W2, W2n, W3);
    // ---- transpose 2, interleaved ----
    lds_order();
#pragma unroll
    for (int t = 0; t < 8; t++) st[72 * g + 9 * t + r] = va[t];
    lds_order();
#pragma unroll
    for (int t = 0; t < 8; t++) va[t] = st[72 * t + l + (l >> 3)];
    lds_order();
#pragma unroll
    for (int t = 0; t < 8; t++) st[72 * g + 9 * t + r] = vb[t];
    lds_order();
#pragma unroll
    for (int t = 0; t < 8; t++) vb[t] = st[72 * t + l + (l >> 3)];
    __sincosf(-(PI_F / 256.0f) * (float)l, &sn, &cs);
    float2 Wc = make_float2(cs, sn);
    float2 w2 = cmul(Wc, Wc);
    float2 w4 = cmul(w2, w2);
    float2 w2n = make_float2(w2.y, -w2.x);
    float2 Wca = cmul(Wc, w64);
    float2 Wcn = make_float2(Wc.y, -Wc.x);
    float2 Wcc = cmul(Wc, w192);
    fft_phaseBC(va, Wc, Wca, Wcn, Wcc, w2, w2n, w4);
    fft_phaseBC(vb, Wc, Wca, Wcn, Wcc, w2, w2n, w4);
}

// Hermitian unpack of one packed-pair FFT into the half2 tile.
__device__ __forceinline__ void unpack_rows(const float2 v[8], __half2* tile,
                                            int lr0, int lr1, int l, int sl) {
#pragma unroll
    for (int t = 0; t <= 4; t++) {
        float2 a = v[7 - t];
        float zfx = __shfl(a.x, sl);
        float zfy = __shfl(a.y, sl);
        if (l == 0) { float2 o = v[(8 - t) & 7]; zfx = o.x; zfy = o.y; }
        float2 z = v[t];
        int col = 64 * t + l;
        if (col < NF) {
            tile[lr0 * 265 + col] = __floats2half2_rn(0.5f * (z.x + zfx), 0.5f * (z.y - zfy));
            tile[lr1 * 265 + col] = __floats2half2_rn(0.5f * (z.y + zfy), 0.5f * (zfx - z.x));
        }
    }
}

// Hermitian unpack with direct fp32 scatter store (hann branch; 16 blocks only).
__device__ __forceinline__ void unpack_rows_store(const float2 v[8], float2* __restrict__ Hrow,
                                                  int r0, int r1, int l, int sl) {
#pragma unroll
    for (int t = 0; t <= 4; t++) {
        float2 a = v[7 - t];
        float zfx = __shfl(a.x, sl);
        float zfy = __shfl(a.y, sl);
        if (l == 0) { float2 o = v[(8 - t) & 7]; zfx = o.x; zfy = o.y; }
        float2 z = v[t];
        int col = 64 * t + l;
        if (col < NF) {
            Hrow[(size_t)col * N + r0] = make_float2(0.5f * (z.x + zfx), 0.5f * (z.y - zfy));
            Hrow[(size_t)col * N + r1] = make_float2(0.5f * (z.y + zfy), 0.5f * (zfx - z.x));
        }
    }
}

// ---------------- zero accumulators ----------------
__global__ void zero_kernel(float* __restrict__ accH, float* __restrict__ bins,
                            float* __restrict__ meanacc) {
    int i = blockIdx.x * blockDim.x + threadIdx.x;
    if (i < NF * N) accH[i] = 0.0f;
    if (i < 2 * (NF + 1)) bins[i] = 0.0f;
    if (i < NB) meanacc[i] = 0.0f;
}

// ---------------- row FFT (512 thr = 8 waves, 32 rows/block) ----
// Hann window computed analytically per lane (no table, no htab loads).
// Blocks [0, NB*16): image rows -> inter (fp16). Blocks [NB*16, NB*16+16):
// Hann-window row FFT -> Hrow (fp32), overlapped with the main grid.
__global__ __launch_bounds__(512, 6) void rowfft_kernel(const float* __restrict__ x,
                                                        float* __restrict__ meanacc,
                                                        __half2* __restrict__ inter,
                                                        float2* __restrict__ Hrow) {
    __shared__ __align__(16) float sm[9216];   // 8 waves x 576 float2 = 36,864 B
    __shared__ float redsum[8];
    int tid = threadIdx.x;
    int w = tid >> 6, l = tid & 63;
    int rl = __brev((unsigned)l) >> 26;                 // brev6(l)
    const int bre[8] = {0, 4, 2, 6, 1, 5, 3, 7};        // brev3(e)
    float2* st = (float2*)sm + w * 576;
    int sl = (64 - l) & 63;
    const float step = (float)N / (float)(N - 1);

    // per-lane column term of the Hann radius (loop-invariant across rows)
    float bb[8];
#pragma unroll
    for (int e = 0; e < 8; e++) {
        float b = (float)((bre[e] << 6) + rl) * step - 256.0f;
        bb[e] = b * b;
    }

    if (blockIdx.x >= NB * 16) {
        // ---- Hann-window FFT branch (16 blocks) ----
        int hb = blockIdx.x - NB * 16;
        int r1 = (hb << 5) + 4 * w;
        float hx[4][8];
#pragma unroll
        for (int j = 0; j < 4; j++) {
            float a = (float)(r1 + j) * step - 256.0f;
            float aa = a * a;
#pragma unroll
            for (int e = 0; e < 8; e++) {
                float rr = sqrtf(aa + bb[e]);
                hx[j][e] = (rr > 256.0f) ? 0.0f : 0.5f * (1.0f + __cosf(rr * (PI_F / 256.0f)));
            }
        }
        float2 va[8], vb[8];
#pragma unroll
        for (int e = 0; e < 8; e++) {
            va[e] = make_float2(hx[0][e], hx[1][e]);
            vb[e] = make_float2(hx[2][e], hx[3][e]);
        }
        fft512_x2(va, vb, st, l);
        unpack_rows_store(va, Hrow, r1, r1 + 1, l, sl);
        unpack_rows_store(vb, Hrow, r1 + 2, r1 + 3, l, sl);
        return;
    }

    int img = blockIdx.x >> 4;
    int rowbase = (blockIdx.x & 15) << 5;
    int r1 = rowbase + 4 * w;
    const float* xp = x + ((size_t)img * N + r1) * N + rl;

    // issue all 32 x-loads first; h computation below is load-independent and
    // fills the load-latency shadow
    float ax[4][8];
#pragma unroll
    for (int j = 0; j < 4; j++)
#pragma unroll
        for (int e = 0; e < 8; e++) ax[j][e] = xp[j * N + (bre[e] << 6)];

    float hx[4][8];
#pragma unroll
    for (int j = 0; j < 4; j++) {
        float a = (float)(r1 + j) * step - 256.0f;
        float aa = a * a;
#pragma unroll
        for (int e = 0; e < 8; e++) {
            float rr = sqrtf(aa + bb[e]);
            hx[j][e] = (rr > 256.0f) ? 0.0f : 0.5f * (1.0f + __cosf(rr * (PI_F / 256.0f)));
        }
    }

    float rsum = 0.0f;
#pragma unroll
    for (int j = 0; j < 4; j++)
#pragma unroll
        for (int e = 0; e < 8; e++) rsum += ax[j][e];

    float2 va[8], vb[8];
#pragma unroll
    for (int e = 0; e < 8; e++) {
        va[e] = make_float2(ax[0][e] * hx[0][e], ax[1][e] * hx[1][e]);
        vb[e] = make_float2(ax[2][e] * hx[2][e], ax[3][e] * hx[3][e]);
    }

#pragma unroll
    for (int off = 32; off > 0; off >>= 1) rsum += __shfl_down(rsum, off);
    if (l == 0) redsum[w] = rsum;

    fft512_x2(va, vb, st, l);
    __syncthreads();   // all waves done with FFT scratch before tile reuse
    if (tid == 0) {
        float s = 0.0f;
#pragma unroll
        for (int i = 0; i < 8; i++) s += redsum[i];
        atomicAdd(meanacc + img, s);
    }

    __half2* tile = (__half2*)sm;    // [32][265]
    unpack_rows(va, tile, 4 * w, 4 * w + 1, l, sl);
    unpack_rows(vb, tile, 4 * w + 2, 4 * w + 3, l, sl);
    __syncthreads();

    // coalesced transposed write: 32 consecutive rows per column (128B lines)
    int c0 = tid >> 5, rr = tid & 31;
#pragma unroll
    for (int it = 0; it < 17; it++) {
        int c = it * 16 + c0;
        if (c < NF) {
            inter[((size_t)img * NF + c) * N + rowbase + rr] = tile[rr * 265 + c];
        }
    }
}

// ---------------- column FFT + |F|^2 half-plane accumulate ----------------
__global__ __launch_bounds__(256, 4) void colfft_kernel(const __half2* __restrict__ inter,
                                                        const float2* __restrict__ Hrow,
                                                        const float* __restrict__ meanacc,
                                                        float* __restrict__ accH) {
    __shared__ __align__(16) float sm[4608];
    int tid = threadIdx.x;
    int w = tid >> 6, l = tid & 63;
    int col = blockIdx.x * 4 + w;
    int colc = col < NF ? col : NF - 1;
    int b0 = blockIdx.y * 4;
    float2* st = (float2*)sm + w * 576;
    int rl = __brev((unsigned)l) >> 26;                 // brev6(l)
    const int bre[8] = {0, 4, 2, 6, 1, 5, 3, 7};        // brev3(e)

    float2 hc[8];
    const float2* hp = Hrow + (size_t)colc * N + rl;
#pragma unroll
    for (int e = 0; e < 8; e++) hc[e] = hp[bre[e] << 6];

    float mn[4];
#pragma unroll
    for (int i = 0; i < 4; i++)
        mn[i] = meanacc[b0 + i] * (1.0f / ((float)N * (float)N));

    float pw[8];
#pragma unroll
    for (int t = 0; t < 8; t++) pw[t] = 0.0f;

    const size_t istr = (size_t)NF * N;
    const __half2* base = inter + ((size_t)b0 * NF + colc) * N + rl;

    __half2 cA[8], cB[8], nA[8], nB[8];
#pragma unroll
    for (int e = 0; e < 8; e++) {
        cA[e] = base[bre[e] << 6];
        cB[e] = base[istr + (bre[e] << 6)];
    }
    __builtin_amdgcn_sched_barrier(0);

#pragma unroll
    for (int it = 0; it < 2; it++) {
        if (it == 0) {
#pragma unroll
            for (int e = 0; e < 8; e++) {
                nA[e] = base[2 * istr + (bre[e] << 6)];
                nB[e] = base[3 * istr + (bre[e] << 6)];
            }
        }
        float mA = mn[2 * it], mB = mn[2 * it + 1];
        float2 va[8], vb[8];
#pragma unroll
        for (int e = 0; e < 8; e++) {
            float2 zA = __half22float2(cA[e]);
            float2 zB = __half22float2(cB[e]);
            va[e] = make_float2(zA.x - mA * hc[e].x, zA.y - mA * hc[e].y);
            vb[e] = make_float2(zB.x - mB * hc[e].x, zB.y - mB * hc[e].y);
        }
        fft512_x2(va, vb, st, l);
#pragma unroll
        for (int t = 0; t < 8; t++)
            pw[t] += va[t].x * va[t].x + va[t].y * va[t].y
                   + vb[t].x * vb[t].x + vb[t].y * vb[t].y;
#pragma unroll
        for (int e = 0; e < 8; e++) { cA[e] = nA[e]; cB[e] = nB[e]; }
    }

    if (col < NF) {
#pragma unroll
        for (int t = 0; t < 8; t++)
            atomicAdd(&accH[(size_t)col * N + 64 * t + l], pw[t]);
    }
}

// ---------------- finalize: nps2D (with Hermitian mirror) + radial bins ------
__global__ __launch_bounds__(256) void finalize2d_kernel(const float* __restrict__ accH,
                                                         float* __restrict__ out2d,
                                                         float* __restrict__ bins) {
    __shared__ float lsum[NF];
    __shared__ float lcnt[NF];
    int t = threadIdx.x;
    for (int i = t; i < NF; i += 256) { lsum[i] = 0.0f; lcnt[i] = 0.0f; }
    __syncthreads();
    const float scale = (0.1f * 0.1f) / ((float)N * (float)N) / (float)NB;
    int idx = blockIdx.x * 256 + t;
    int stride = gridDim.x * 256;
    for (int p = idx; p < N * N; p += stride) {
        int i = p >> 9, j = p & (N - 1);
        int jm = (j + 256) & 511;
        int col, k;
        if (jm < NF) { col = jm; k = (i + 256) & 511; }        // direct half-plane
        else         { col = 256 - j; k = (256 - i) & 511; }   // Hermitian mirror
        float v = accH[((size_t)col << 9) + k] * scale;
        out2d[p] = v;                                           // coalesced store
        float xi = (float)(i - 256), yj = (float)(j - 256);
        int rad = (int)rintf(sqrtf(xi * xi + yj * yj));
        if (rad < NF) { atomicAdd(&lsum[rad], v); atomicAdd(&lcnt[rad], 1.0f); }
    }
    __syncthreads();
    for (int i = t; i < NF; i += 256) {
        if (lsum[i] != 0.0f || lcnt[i] != 0.0f) {
            atomicAdd(&bins[i], lsum[i]);
            atomicAdd(&bins[NF + 1 + i], lcnt[i]);
        }
    }
}

// ---------------- finalize: nps1D + f1D ----------------
__global__ void finalize1d_kernel(const float* __restrict__ bins, float* __restrict__ out) {
    int t = blockIdx.x * blockDim.x + threadIdx.x;
    if (t < NF) {
        out[t] = bins[t] / bins[NF + 1 + t];                 // nps1D
        out[NF + N * N + t] = (float)t * (5.0f / 256.0f);    // f1D (nyquist = 5)
    }
}

extern "C" void kernel_launch(void* const* d_in, const int* in_sizes, int n_in,
                              void* d_out, int out_size, void* d_ws, size_t ws_size,
                              hipStream_t stream) {
    const float* x = (const float*)d_in[0];
    float* out = (float*)d_out;
    char* ws = (char*)d_ws;

    float* accH    = (float*)ws;                                     // NF*N floats
    float* meanacc = (float*)(ws + (size_t)NF * N * sizeof(float));  // NB floats
    float* bins    = meanacc + NB;                                   // 2*(NF+1) floats
    size_t off_h = (size_t)NF * N * sizeof(float) + NB * sizeof(float)
                   + 2 * (NF + 1) * sizeof(float);
    off_h = (off_h + 255) & ~(size_t)255;
    float2* Hrow = (float2*)(ws + off_h);                            // [NF][N] float2 ~ 1.05 MB
    size_t off_inter = off_h + (size_t)NF * N * sizeof(float2);
    off_inter = (off_inter + 255) & ~(size_t)255;
    __half2* inter = (__half2*)(ws + off_inter);   // [NB][NF][N] half2 = 67.4 MB

    zero_kernel<<<dim3((NF * N + 255) / 256), dim3(256), 0, stream>>>(accH, bins, meanacc);
    rowfft_kernel<<<dim3(NB * 16 + 16), dim3(512), 0, stream>>>(x, meanacc, inter, Hrow);
    colfft_kernel<<<dim3(65, 32), dim3(256), 0, stream>>>(inter, Hrow, meanacc, accH);
    finalize2d_kernel<<<dim3(512), dim3(256), 0, stream>>>(accH, out + NF, bins);
    finalize1d_kernel<<<dim3(2), dim3(256), 0, stream>>>(bins, out);
}